// Round 6
// baseline (123534.009 us; speedup 1.0000x reference)
//
#include <hip/hip_runtime.h>
#include <math.h>

// ODE-RNN, T=8192, IN=512, H=1024, OUT=256, 4 euler substeps/step.
// R5: per-phase latency attack. 6 cross-WG handoffs/step (structural floor
// of the pre-activation factorization):
//   z = W_f1 h + b_f1, y = W_h h, M = W_f1 W_f2, P = W_h W_f2 (precomputed)
//   4x substep: publish u=tanh(z); z += dt(M u + c1); y += dt(P u + c2)
//   cell: publish a = tanh(y4 + W_in x + b); publish h' = tanh(W_h2 a + b_h2)
//   reset z,y from h' (no factorization error accumulation across steps)
// New this round:
//   - 256 WGs x 64 threads (1 wave each, 4 rows/wave): no __syncthreads, no
//     LDS; each wave polls the full queue into registers, __all() to break.
//   - M,P,W_in register-resident: zero memory ops on the post-detect path
//     for phases 1-4; poll sweeps never queue behind weight prefetches.
// Handoff = epoch-tagged 8B agent atomics (tag<<32 | f32 bits).
// WAR-safe: full-read ring (every wave produces into every queue; queue
// reuse distance >= 2 complete broadcast consumptions).

#define TSTEPS 8192
#define INP    512
#define HDIM   1024
#define OUTD   256
#define NWG    256
#define BLK    64

typedef unsigned long long u64;
typedef unsigned int u32;

__device__ __forceinline__ u64 aload(u64* p) {
    return __hip_atomic_load(p, __ATOMIC_RELAXED, __HIP_MEMORY_SCOPE_AGENT);
}
__device__ __forceinline__ void astore(u64* p, u64 v) {
    __hip_atomic_store(p, v, __ATOMIC_RELAXED, __HIP_MEMORY_SCOPE_AGENT);
}
__device__ __forceinline__ u64 pack(u32 tag, float f) {
    return ((u64)tag << 32) | (u64)__float_as_uint(f);
}

// ---------------- precompute: C = A @ B, 1024x1024x1024 fp32 ----------------
__global__ __launch_bounds__(256)
void mm1024(const float* __restrict__ A, const float* __restrict__ B,
            float* __restrict__ C) {
    __shared__ float As[64][17];
    __shared__ float Bs[16][65];
    const int tid = threadIdx.x;
    const int tx = tid & 15, ty = tid >> 4;
    const int r0 = blockIdx.y * 64, c0 = blockIdx.x * 64;
    float acc[4][4] = {};
    for (int k0 = 0; k0 < HDIM; k0 += 16) {
        const int ar = tid >> 2, ac = (tid & 3) * 4;
        const float4 av = *reinterpret_cast<const float4*>(
            A + (size_t)(r0 + ar) * HDIM + k0 + ac);
        As[ar][ac] = av.x; As[ar][ac + 1] = av.y;
        As[ar][ac + 2] = av.z; As[ar][ac + 3] = av.w;
        const int br = tid >> 4, bc = (tid & 15) * 4;
        const float4 bv = *reinterpret_cast<const float4*>(
            B + (size_t)(k0 + br) * HDIM + c0 + bc);
        Bs[br][bc] = bv.x; Bs[br][bc + 1] = bv.y;
        Bs[br][bc + 2] = bv.z; Bs[br][bc + 3] = bv.w;
        __syncthreads();
        #pragma unroll
        for (int kk = 0; kk < 16; ++kk) {
            float a[4], b[4];
            #pragma unroll
            for (int i2 = 0; i2 < 4; ++i2) a[i2] = As[ty * 4 + i2][kk];
            #pragma unroll
            for (int j2 = 0; j2 < 4; ++j2) b[j2] = Bs[kk][tx * 4 + j2];
            #pragma unroll
            for (int i2 = 0; i2 < 4; ++i2)
                #pragma unroll
                for (int j2 = 0; j2 < 4; ++j2)
                    acc[i2][j2] = fmaf(a[i2], b[j2], acc[i2][j2]);
        }
        __syncthreads();
    }
    #pragma unroll
    for (int i2 = 0; i2 < 4; ++i2)
        #pragma unroll
        for (int j2 = 0; j2 < 4; ++j2)
            C[(size_t)(r0 + ty * 4 + i2) * HDIM + c0 + tx * 4 + j2] = acc[i2][j2];
}

// ---------------------------- persistent kernel -----------------------------
__global__ __launch_bounds__(BLK, 1)
void ode_rnn_persistent(
    const float* __restrict__ t,    const float* __restrict__ x,
    const float* __restrict__ W_in, const float* __restrict__ b_in,
    const float* __restrict__ W_h,  const float* __restrict__ b_h,
    const float* __restrict__ W_h2, const float* __restrict__ b_h2,
    const float* __restrict__ W_f1, const float* __restrict__ b_f1,
    const float* __restrict__ b_f2,
    const float* __restrict__ W_dec, const float* __restrict__ b_dec,
    const float* __restrict__ Mw,   const float* __restrict__ Pw,
    float* __restrict__ out,
    u64* QA, u64* QB, u64* QC, u64* QD)
{
    const int lane = threadIdx.x;        // 0..63
    const int gw   = blockIdx.x;         // 0..255 (one wave per WG)
    const int r0   = gw * 4;             // 4 owned rows

    // ---- helpers (all static indexing, all 64-lane wave ops) ----
    auto bflyAll = [&](float& a) {
        #pragma unroll
        for (int off = 32; off; off >>= 1) a += __shfl_xor(a, off);
    };
    auto sel4 = [&](const float (&a)[4]) {
        float s = a[0];
        s = (lane == 1) ? a[1] : s;
        s = (lane == 2) ? a[2] : s;
        s = (lane == 3) ? a[3] : s;
        return s;
    };
    auto pubTanh = [&](u64* q, u32 e, float pre) {
        if (lane < 4) astore(&q[r0 + lane], pack(e, tanhf(pre)));
    };
    auto waitq = [&](u64* q, u32 tag, u64 (&v)[16]) {
        for (;;) {
            #pragma unroll
            for (int j = 0; j < 16; ++j) v[j] = aload(q + j * 64 + lane);
            bool ok = true;
            #pragma unroll
            for (int j = 0; j < 16; ++j) ok &= ((u32)(v[j] >> 32) == tag);
            if (__all(ok)) break;
        }
    };
    auto loadRows16 = [&](const float* __restrict__ W, float (&w)[4][16]) {
        #pragma unroll
        for (int r = 0; r < 4; ++r)
            #pragma unroll
            for (int j = 0; j < 16; ++j)
                w[r][j] = W[(size_t)(r0 + r) * HDIM + j * 64 + lane];
    };
    auto dotDual = [&](const float (&wa)[4][16], const float (&wb)[4][16],
                       const u64 (&v)[16], float (&oa)[4], float (&ob)[4]) {
        float aa[4] = {}, ab[4] = {};
        #pragma unroll
        for (int j = 0; j < 16; ++j) {
            const float uv = __uint_as_float((u32)v[j]);
            #pragma unroll
            for (int r = 0; r < 4; ++r) {
                aa[r] = fmaf(wa[r][j], uv, aa[r]);
                ab[r] = fmaf(wb[r][j], uv, ab[r]);
            }
        }
        #pragma unroll
        for (int off = 32; off; off >>= 1)
            #pragma unroll
            for (int r = 0; r < 4; ++r) {
                aa[r] += __shfl_xor(aa[r], off);
                ab[r] += __shfl_xor(ab[r], off);
            }
        #pragma unroll
        for (int r = 0; r < 4; ++r) { oa[r] = aa[r]; ob[r] = ab[r]; }
    };
    auto dotOne = [&](const float (&wa)[4][16], const u64 (&v)[16],
                      float (&oa)[4]) {
        float aa[4] = {};
        #pragma unroll
        for (int j = 0; j < 16; ++j) {
            const float uv = __uint_as_float((u32)v[j]);
            #pragma unroll
            for (int r = 0; r < 4; ++r) aa[r] = fmaf(wa[r][j], uv, aa[r]);
        }
        #pragma unroll
        for (int off = 32; off; off >>= 1)
            #pragma unroll
            for (int r = 0; r < 4; ++r) aa[r] += __shfl_xor(aa[r], off);
        #pragma unroll
        for (int r = 0; r < 4; ++r) oa[r] = aa[r];
    };

    // ---- permanent register state ----
    float m[4][16], p[4][16];            // M,P row slices: zero mem ops in
    loadRows16(Mw, m);                   // the substep critical path
    loadRows16(Pw, p);
    float wir[4][8];                     // W_in rows (permanent)
    #pragma unroll
    for (int r = 0; r < 4; ++r)
        #pragma unroll
        for (int j = 0; j < 8; ++j)
            wir[r][j] = W_in[(size_t)(r0 + r) * INP + j * 64 + lane];

    float bf1r[4], bihr[4], bh2r[4];
    #pragma unroll
    for (int r = 0; r < 4; ++r) {
        bf1r[r] = b_f1[r0 + r];
        bihr[r] = b_in[r0 + r] + b_h[r0 + r];
        bh2r[r] = b_h2[r0 + r];
    }

    // c1 = (W_f1 b_f2)[rows], c2 = (W_h b_f2)[rows] — once, off critical path
    float c1[4], c2[4];
    {
        float bv[16];
        #pragma unroll
        for (int j = 0; j < 16; ++j) bv[j] = b_f2[j * 64 + lane];
        float wt[4][16];
        loadRows16(W_f1, wt);
        #pragma unroll
        for (int r = 0; r < 4; ++r) {
            float a = 0.f;
            #pragma unroll
            for (int j = 0; j < 16; ++j) a = fmaf(wt[r][j], bv[j], a);
            bflyAll(a); c1[r] = a;
        }
        loadRows16(W_h, wt);
        #pragma unroll
        for (int r = 0; r < 4; ++r) {
            float a = 0.f;
            #pragma unroll
            for (int j = 0; j < 16; ++j) a = fmaf(wt[r][j], bv[j], a);
            bflyAll(a); c2[r] = a;
        }
    }

    float z[4], y[4];
    #pragma unroll
    for (int r = 0; r < 4; ++r) { z[r] = bf1r[r]; y[r] = 0.f; }

    u32 eA = 0, eB = 0, eC = 0, eD = 0;
    u64 v[16];
    float xr[8];
    float wbufA[4][16], wbufB[4][16];

    auto odeSub = [&](u64* q, u32 e, float dt) {
        pubTanh(q, e, sel4(z));
        waitq(q, e, v);
        float md[4], pd[4];
        dotDual(m, p, v, md, pd);
        #pragma unroll
        for (int r = 0; r < 4; ++r) {
            z[r] = fmaf(dt, md[r] + c1[r], z[r]);
            y[r] = fmaf(dt, pd[r] + c2[r], y[r]);
        }
    };

    #pragma unroll 1
    for (int i = 1; i < TSTEPS; ++i) {
        const float dt = (t[i] - t[i - 1]) * 0.25f;
        const float* xrow = x + (size_t)i * INP;

        odeSub(QA, ++eA, dt);                       // phase 1 (u1)
        #pragma unroll
        for (int j = 0; j < 8; ++j) xr[j] = xrow[j * 64 + lane];  // 2 phases slack
        odeSub(QB, ++eB, dt);                       // phase 2 (u2)
        odeSub(QA, ++eA, dt);                       // phase 3 (u3)

        // phase 4 (u4): z dead after publish; consume P only -> y4 -> a
        ++eB;
        pubTanh(QB, eB, sel4(z));
        float winx[4];
        {
            float aw[4] = {};
            #pragma unroll
            for (int j = 0; j < 8; ++j)
                #pragma unroll
                for (int r = 0; r < 4; ++r)
                    aw[r] = fmaf(wir[r][j], xr[j], aw[r]);
            #pragma unroll
            for (int off = 32; off; off >>= 1)
                #pragma unroll
                for (int r = 0; r < 4; ++r) aw[r] += __shfl_xor(aw[r], off);
            #pragma unroll
            for (int r = 0; r < 4; ++r) winx[r] = aw[r];
        }
        waitq(QB, eB, v);
        float pd[4];
        dotOne(p, v, pd);
        float apre[4];
        #pragma unroll
        for (int r = 0; r < 4; ++r)
            apre[r] = fmaf(dt, pd[r] + c2[r], y[r]) + winx[r] + bihr[r];

        // phase 5 (a): consume W_h2 @ a
        ++eC;
        pubTanh(QC, eC, sel4(apre));
        loadRows16(W_h2, wbufA);                    // stream overlaps poll
        waitq(QC, eC, v);
        float hd[4];
        dotOne(wbufA, v, hd);
        float hpre[4];
        #pragma unroll
        for (int r = 0; r < 4; ++r) hpre[r] = hd[r] + bh2r[r];

        // phase 6 (h'): consume z' = W_f1 h' + b_f1, y' = W_h h'
        ++eD;
        pubTanh(QD, eD, sel4(hpre));
        loadRows16(W_f1, wbufA);                    // streams overlap poll
        loadRows16(W_h, wbufB);
        waitq(QD, eD, v);
        float zd[4], yd[4];
        dotDual(wbufA, wbufB, v, zd, yd);
        #pragma unroll
        for (int r = 0; r < 4; ++r) { z[r] = zd[r] + bf1r[r]; y[r] = yd[r]; }
    }

    // ---- decoder: out[gw] = W_dec[gw,:] @ h_T + b_dec[gw] ----
    waitq(QD, eD, v);                               // tags already match
    {
        float acc = 0.f;
        #pragma unroll
        for (int j = 0; j < 16; ++j) {
            const float w = W_dec[(size_t)gw * HDIM + j * 64 + lane];
            acc = fmaf(w, __uint_as_float((u32)v[j]), acc);
        }
        bflyAll(acc);
        if (lane == 0) out[gw] = acc + b_dec[gw];
    }
}

extern "C" void kernel_launch(void* const* d_in, const int* in_sizes, int n_in,
                              void* d_out, int out_size, void* d_ws, size_t ws_size,
                              hipStream_t stream) {
    const float* t     = (const float*)d_in[0];
    const float* x     = (const float*)d_in[1];
    const float* W_in  = (const float*)d_in[2];
    const float* b_in  = (const float*)d_in[3];
    const float* W_h   = (const float*)d_in[4];
    const float* b_h   = (const float*)d_in[5];
    const float* W_h2  = (const float*)d_in[6];
    const float* b_h2  = (const float*)d_in[7];
    const float* W_f1  = (const float*)d_in[8];
    const float* b_f1  = (const float*)d_in[9];
    const float* W_f2  = (const float*)d_in[10];
    const float* b_f2  = (const float*)d_in[11];
    const float* W_dec = (const float*)d_in[12];
    const float* b_dec = (const float*)d_in[13];
    float* out = (float*)d_out;

    // ws layout: M (4MB) | P (4MB) | QA,QB,QC,QD (4 x 8KB)
    unsigned char* ws = (unsigned char*)d_ws;
    float* Mw = (float*)(ws);
    float* Pw = (float*)(ws + (size_t)4 * 1024 * 1024);
    u64*   QA = (u64*)(ws + (size_t)8 * 1024 * 1024);
    u64*   QB = QA + HDIM;
    u64*   QC = QB + HDIM;
    u64*   QD = QC + HDIM;

    // precompute M = W_f1 @ W_f2, P = W_h @ W_f2 (every call; deterministic)
    mm1024<<<dim3(16, 16), 256, 0, stream>>>(W_f1, W_f2, Mw);
    mm1024<<<dim3(16, 16), 256, 0, stream>>>(W_h,  W_f2, Pw);

    // reset epoch tags to 0 (first expected tag is 1); every call
    hipMemsetAsync(ws + (size_t)8 * 1024 * 1024, 0, 4 * HDIM * sizeof(u64), stream);

    ode_rnn_persistent<<<dim3(NWG), dim3(BLK), 0, stream>>>(
        t, x, W_in, b_in, W_h, b_h, W_h2, b_h2, W_f1, b_f1, b_f2,
        W_dec, b_dec, Mw, Pw, out, QA, QB, QC, QD);
}

// Round 7
// 105260.217 us; speedup vs baseline: 1.1736x; 1.1736x over previous
//
#include <hip/hip_runtime.h>
#include <math.h>

// ODE-RNN, T=8192, IN=512, H=1024, OUT=256, 4 euler substeps/step.
// R7 = R4's 64WGx256 structure + 8x-replicated queues + reg-resident M/P/W_in.
//   z = W_f1 h + b_f1, y = W_h h, M = W_f1 W_f2, P = W_h W_f2 (precomputed)
//   4x substep: publish u=tanh(z); z += dt(M u + c1); y += dt(P u + c2)
//   cell: publish a = tanh(y4 + W_in x + b); publish h' = tanh(W_h2 a + b_h2)
//   z,y reset from h' each step (no factorization error accumulation).
// Handoff: epoch-tagged 8B agent atomics (tag<<32|f32), 8 replicas per queue.
// Publishers write all replicas (one store inst, lanes seg<8); each WG polls
// only replica wg&7 -> 8 readers/line (was 64). WAR-safe per replica via the
// full-read ring (reader's next publish gates the writer's overwrite).

#define TSTEPS 8192
#define INP    512
#define HDIM   1024
#define OUTD   256
#define NWG    64
#define BLK    256
#define NREP   8

typedef unsigned long long u64;
typedef unsigned int u32;

__device__ __forceinline__ u64 aload(u64* p) {
    return __hip_atomic_load(p, __ATOMIC_RELAXED, __HIP_MEMORY_SCOPE_AGENT);
}
__device__ __forceinline__ void astore(u64* p, u64 v) {
    __hip_atomic_store(p, v, __ATOMIC_RELAXED, __HIP_MEMORY_SCOPE_AGENT);
}
__device__ __forceinline__ u64 pack(u32 tag, float f) {
    return ((u64)tag << 32) | (u64)__float_as_uint(f);
}

// ---------------- precompute: C = A @ B, 1024x1024x1024 fp32 ----------------
__global__ __launch_bounds__(256)
void mm1024(const float* __restrict__ A, const float* __restrict__ B,
            float* __restrict__ C) {
    __shared__ float As[64][17];
    __shared__ float Bs[16][65];
    const int tid = threadIdx.x;
    const int tx = tid & 15, ty = tid >> 4;
    const int r0 = blockIdx.y * 64, c0 = blockIdx.x * 64;
    float acc[4][4] = {};
    for (int k0 = 0; k0 < HDIM; k0 += 16) {
        const int ar = tid >> 2, ac = (tid & 3) * 4;
        const float4 av = *reinterpret_cast<const float4*>(
            A + (size_t)(r0 + ar) * HDIM + k0 + ac);
        As[ar][ac] = av.x; As[ar][ac + 1] = av.y;
        As[ar][ac + 2] = av.z; As[ar][ac + 3] = av.w;
        const int br = tid >> 4, bc = (tid & 15) * 4;
        const float4 bv = *reinterpret_cast<const float4*>(
            B + (size_t)(k0 + br) * HDIM + c0 + bc);
        Bs[br][bc] = bv.x; Bs[br][bc + 1] = bv.y;
        Bs[br][bc + 2] = bv.z; Bs[br][bc + 3] = bv.w;
        __syncthreads();
        #pragma unroll
        for (int kk = 0; kk < 16; ++kk) {
            float a[4], b[4];
            #pragma unroll
            for (int i2 = 0; i2 < 4; ++i2) a[i2] = As[ty * 4 + i2][kk];
            #pragma unroll
            for (int j2 = 0; j2 < 4; ++j2) b[j2] = Bs[kk][tx * 4 + j2];
            #pragma unroll
            for (int i2 = 0; i2 < 4; ++i2)
                #pragma unroll
                for (int j2 = 0; j2 < 4; ++j2)
                    acc[i2][j2] = fmaf(a[i2], b[j2], acc[i2][j2]);
        }
        __syncthreads();
    }
    #pragma unroll
    for (int i2 = 0; i2 < 4; ++i2)
        #pragma unroll
        for (int j2 = 0; j2 < 4; ++j2)
            C[(size_t)(r0 + ty * 4 + i2) * HDIM + c0 + tx * 4 + j2] = acc[i2][j2];
}

// ---------------------------- persistent kernel -----------------------------
__global__ __launch_bounds__(BLK, 1)
void ode_rnn_persistent(
    const float* __restrict__ t,    const float* __restrict__ x,
    const float* __restrict__ W_in, const float* __restrict__ b_in,
    const float* __restrict__ W_h,  const float* __restrict__ b_h,
    const float* __restrict__ W_h2, const float* __restrict__ b_h2,
    const float* __restrict__ W_f1, const float* __restrict__ b_f1,
    const float* __restrict__ b_f2,
    const float* __restrict__ W_dec, const float* __restrict__ b_dec,
    const float* __restrict__ Mw,   const float* __restrict__ Pw,
    float* __restrict__ out,
    u64* QA, u64* QB, u64* QC, u64* QD)
{
    __shared__ __align__(16) float lds[HDIM];
    const int tid = threadIdx.x;
    const int wg  = blockIdx.x;
    const int seg = tid & 15;                 // 16 lanes per row
    const int row = wg * 16 + (tid >> 4);     // owned row
    const int rep = wg & (NREP - 1);          // replica this WG polls

    // Publish: tanh(pre) to all 8 replicas in ONE store instruction
    // (lanes seg<8 each write replica `seg`). All 16 lanes hold `pre`
    // (butterfly reductions), so no lane shuffle is needed.
    auto publish = [&](u64* q, u32 e, float pre) {
        if (seg < 8) astore(q + (size_t)seg * HDIM + row, pack(e, tanhf(pre)));
    };

    // Poll own replica (4 concurrent slots/thread) into LDS.
    auto stage = [&](u64* q, u32 tag) {
        u64* base = q + (size_t)rep * HDIM;
        __syncthreads();
        const int i0 = tid, i1 = tid + 256, i2 = tid + 512, i3 = tid + 768;
        u64 v0, v1, v2, v3;
        for (;;) {
            v0 = aload(base + i0); v1 = aload(base + i1);
            v2 = aload(base + i2); v3 = aload(base + i3);
            const bool ok = ((u32)(v0 >> 32) == tag) & ((u32)(v1 >> 32) == tag) &
                            ((u32)(v2 >> 32) == tag) & ((u32)(v3 >> 32) == tag);
            if (ok) break;
        }
        lds[i0] = __uint_as_float((u32)v0); lds[i1] = __uint_as_float((u32)v1);
        lds[i2] = __uint_as_float((u32)v2); lds[i3] = __uint_as_float((u32)v3);
        __syncthreads();
    };

    auto pref16 = [&](const float* W, float4 (&w)[16]) {
        const float4* pW = reinterpret_cast<const float4*>(W + (size_t)row * HDIM);
        #pragma unroll
        for (int j = 0; j < 16; ++j) w[j] = pW[j * 16 + seg];
    };
    auto red16 = [&](float a) {           // butterfly: ALL 16 lanes get the sum
        #pragma unroll
        for (int off = 8; off; off >>= 1) a += __shfl_xor(a, off, 16);
        return a;
    };
    auto dotLds = [&](const float4 (&w)[16]) {
        float a = 0.f;
        #pragma unroll
        for (int j = 0; j < 16; ++j) {
            const float4 v = *reinterpret_cast<const float4*>(lds + j * 64 + seg * 4);
            a = fmaf(w[j].x, v.x, a); a = fmaf(w[j].y, v.y, a);
            a = fmaf(w[j].z, v.z, a); a = fmaf(w[j].w, v.w, a);
        }
        return red16(a);
    };
    auto dotLds2 = [&](const float4 (&wa)[16], const float4 (&wb)[16],
                       float& oa, float& ob) {
        float a = 0.f, b = 0.f;
        #pragma unroll
        for (int j = 0; j < 16; ++j) {
            const float4 v = *reinterpret_cast<const float4*>(lds + j * 64 + seg * 4);
            a = fmaf(wa[j].x, v.x, a); a = fmaf(wa[j].y, v.y, a);
            a = fmaf(wa[j].z, v.z, a); a = fmaf(wa[j].w, v.w, a);
            b = fmaf(wb[j].x, v.x, b); b = fmaf(wb[j].y, v.y, b);
            b = fmaf(wb[j].z, v.z, b); b = fmaf(wb[j].w, v.w, b);
        }
        oa = red16(a); ob = red16(b);
    };

    // ---- permanent register weights: zero pre-poll mem ops in phases 1-4 ----
    float4 m16[16], p16[16], wir[8];
    pref16(Mw, m16);
    pref16(Pw, p16);
    {
        const float4* pW = reinterpret_cast<const float4*>(W_in + (size_t)row * INP);
        #pragma unroll
        for (int j = 0; j < 8; ++j) wir[j] = pW[j * 16 + seg];
    }

    const float bf1_r = b_f1[row];
    const float bih_r = b_in[row] + b_h[row];
    const float bh2_r = b_h2[row];

    float4 wbufA[16], wbufB[16];

    // c1 = (W_f1 b_f2)[row], c2 = (W_h b_f2)[row] — once, off critical path
    float c1_own, c2_own;
    {
        #pragma unroll
        for (int k = 0; k < 4; ++k) lds[tid + k * 256] = b_f2[tid + k * 256];
        __syncthreads();
        pref16(W_f1, wbufA); c1_own = dotLds(wbufA);
        pref16(W_h,  wbufA); c2_own = dotLds(wbufA);
    }

    float z_own = bf1_r;                  // z0 = W_f1*0 + b_f1
    float y_own = 0.f;                    // y0 = W_h*0
    u32 eA = 0, eB = 0, eC = 0, eD = 0;
    float4 xr[8];

    #pragma unroll 1
    for (int i = 1; i < TSTEPS; ++i) {
        const float dt = (t[i] - t[i - 1]) * 0.25f;

        // ---- phase 1 (u1 -> QA): z,y += dt(M/P u + c)
        ++eA;
        publish(QA, eA, z_own);
        stage(QA, eA);
        {   // x row loads issue AFTER detect: overlap ph1-3 compute+polls
            const float4* xp = reinterpret_cast<const float4*>(x + (size_t)i * INP);
            #pragma unroll
            for (int j = 0; j < 8; ++j) xr[j] = xp[j * 16 + seg];
        }
        {
            float md, pd; dotLds2(m16, p16, md, pd);
            z_own = fmaf(dt, md + c1_own, z_own);
            y_own = fmaf(dt, pd + c2_own, y_own);
        }

        // ---- phase 2 (u2 -> QB)
        ++eB;
        publish(QB, eB, z_own);
        stage(QB, eB);
        {
            float md, pd; dotLds2(m16, p16, md, pd);
            z_own = fmaf(dt, md + c1_own, z_own);
            y_own = fmaf(dt, pd + c2_own, y_own);
        }

        // ---- phase 3 (u3 -> QA)
        ++eA;
        publish(QA, eA, z_own);
        stage(QA, eA);
        {
            float md, pd; dotLds2(m16, p16, md, pd);
            z_own = fmaf(dt, md + c1_own, z_own);
            y_own = fmaf(dt, pd + c2_own, y_own);
        }

        // ---- phase 4 (u4 -> QB): z dead after publish; P only -> y4 -> a
        ++eB;
        publish(QB, eB, z_own);
        float winx;                        // W_in @ x_i: pure VALU under poll
        {
            float a = 0.f;
            #pragma unroll
            for (int j = 0; j < 8; ++j) {
                a = fmaf(wir[j].x, xr[j].x, a); a = fmaf(wir[j].y, xr[j].y, a);
                a = fmaf(wir[j].z, xr[j].z, a); a = fmaf(wir[j].w, xr[j].w, a);
            }
            winx = red16(a);
        }
        stage(QB, eB);
        pref16(W_h2, wbufA);               // stream drains under ph4 compute
        float apre;
        {
            const float pd = dotLds(p16);
            apre = fmaf(dt, pd + c2_own, y_own) + winx + bih_r;
        }

        // ---- phase 5 (a -> QC): h' = tanh(W_h2 a + b_h2)
        ++eC;
        publish(QC, eC, apre);
        stage(QC, eC);
        pref16(W_f1, wbufB);               // drains under ph5 compute
        const float hpre = dotLds(wbufA) + bh2_r;

        // ---- phase 6 (h' -> QD): z' = W_f1 h' + b_f1, y' = W_h h'
        ++eD;
        publish(QD, eD, hpre);
        pref16(W_h, wbufA);                // drains under visibility delay
        stage(QD, eD);
        {
            float zd, yd; dotLds2(wbufB, wbufA, zd, yd);
            z_own = zd + bf1_r;
            y_own = yd;
        }
    }

    // ---- decoder: lds still holds h_T from the last phase-6 stage ----
    {
        const int rl = tid >> 6, s2 = tid & 63;
        const int orow = wg * 4 + rl;
        const float4* wd = reinterpret_cast<const float4*>(W_dec + (size_t)orow * HDIM);
        float acc = 0.f;
        #pragma unroll
        for (int j = 0; j < 4; ++j) {
            const float4 w = wd[j * 64 + s2];
            const float4 v = *reinterpret_cast<const float4*>(lds + j * 256 + s2 * 4);
            acc = fmaf(w.x, v.x, acc); acc = fmaf(w.y, v.y, acc);
            acc = fmaf(w.z, v.z, acc); acc = fmaf(w.w, v.w, acc);
        }
        #pragma unroll
        for (int off = 32; off; off >>= 1) acc += __shfl_down(acc, off, 64);
        if (s2 == 0) out[orow] = acc + b_dec[orow];
    }
}

extern "C" void kernel_launch(void* const* d_in, const int* in_sizes, int n_in,
                              void* d_out, int out_size, void* d_ws, size_t ws_size,
                              hipStream_t stream) {
    const float* t     = (const float*)d_in[0];
    const float* x     = (const float*)d_in[1];
    const float* W_in  = (const float*)d_in[2];
    const float* b_in  = (const float*)d_in[3];
    const float* W_h   = (const float*)d_in[4];
    const float* b_h   = (const float*)d_in[5];
    const float* W_h2  = (const float*)d_in[6];
    const float* b_h2  = (const float*)d_in[7];
    const float* W_f1  = (const float*)d_in[8];
    const float* b_f1  = (const float*)d_in[9];
    const float* W_f2  = (const float*)d_in[10];
    const float* b_f2  = (const float*)d_in[11];
    const float* W_dec = (const float*)d_in[12];
    const float* b_dec = (const float*)d_in[13];
    float* out = (float*)d_out;

    // ws layout: M (4MB) | P (4MB) | QA,QB,QC,QD (4 queues x 8 replicas x 8KB)
    unsigned char* ws = (unsigned char*)d_ws;
    float* Mw = (float*)(ws);
    float* Pw = (float*)(ws + (size_t)4 * 1024 * 1024);
    u64*   QA = (u64*)(ws + (size_t)8 * 1024 * 1024);
    u64*   QB = QA + (size_t)NREP * HDIM;
    u64*   QC = QB + (size_t)NREP * HDIM;
    u64*   QD = QC + (size_t)NREP * HDIM;

    // precompute M = W_f1 @ W_f2, P = W_h @ W_f2 (every call; deterministic)
    mm1024<<<dim3(16, 16), 256, 0, stream>>>(W_f1, W_f2, Mw);
    mm1024<<<dim3(16, 16), 256, 0, stream>>>(W_h,  W_f2, Pw);

    // reset all replica tags to 0 (first expected tag is 1); every call
    hipMemsetAsync(ws + (size_t)8 * 1024 * 1024, 0,
                   (size_t)4 * NREP * HDIM * sizeof(u64), stream);

    ode_rnn_persistent<<<dim3(NWG), dim3(BLK), 0, stream>>>(
        t, x, W_in, b_in, W_h, b_h, W_h2, b_h2, W_f1, b_f1, b_f2,
        W_dec, b_dec, Mw, Pw, out, QA, QB, QC, QD);
}